// Round 1
// baseline (301.598 us; speedup 1.0000x reference)
//
#include <hip/hip_runtime.h>

#define CLAMP_THR 0.9999999f

constexpr int ELEMS = 256;        // elements per chunk == blockDim.x
constexpr int FLTS  = ELEMS * 9;  // 2304 floats per matrix per chunk

__global__ void zero_loss_kernel(float* out) {
    if (threadIdx.x == 0) out[0] = 0.0f;
}

__global__ __launch_bounds__(256) void geodesic_grad_kernel(
    const float* __restrict__ Rrel,   // [N,3,3]
    const float* __restrict__ Rw1,    // [N,3,3]  (R_w2c1)
    const float* __restrict__ Rw2,    // [N,3,3]  (R_w2c2)
    float* __restrict__ out,          // [1 + 9N + 9N]
    int n)
{
    __shared__ float lA[FLTS];  // stages R_rel, then d_R_w2c1
    __shared__ float lB[FLTS];  // stages R_w2c2, then d_R_w2c2
    __shared__ float lC[FLTS];  // stages R_w2c1
    __shared__ float wsum[4];

    const int t = threadIdx.x;
    float* __restrict__ out1 = out + 1;                    // d_R_w2c1
    float* __restrict__ out2 = out + 1 + (size_t)n * 9;    // d_R_w2c2

    float local_loss = 0.0f;
    const int nChunks = (n + ELEMS - 1) / ELEMS;

    for (int c = blockIdx.x; c < nChunks; c += gridDim.x) {
        const size_t base = (size_t)c * FLTS;
        const int valid = min(ELEMS, n - c * ELEMS);
        const int vf = valid * 9;

        // ---- global -> LDS staging (coalesced) ----
        if (valid == ELEMS) {
            const float4* gA = reinterpret_cast<const float4*>(Rrel + base);
            const float4* gB = reinterpret_cast<const float4*>(Rw2 + base);
            const float4* gC = reinterpret_cast<const float4*>(Rw1 + base);
            float4* sA = reinterpret_cast<float4*>(lA);
            float4* sB = reinterpret_cast<float4*>(lB);
            float4* sC = reinterpret_cast<float4*>(lC);
            #pragma unroll
            for (int i = t; i < FLTS / 4; i += 256) {
                sA[i] = gA[i];
                sB[i] = gB[i];
                sC[i] = gC[i];
            }
        } else {
            for (int i = t; i < vf; i += 256) {
                lA[i] = Rrel[base + i];
                lB[i] = Rw2[base + i];
                lC[i] = Rw1[base + i];
            }
        }
        __syncthreads();

        // ---- per-element compute (each thread owns LDS slots [9t, 9t+9)) ----
        if (t < valid) {
            float R[9], A[9], B[9];
            #pragma unroll
            for (int j = 0; j < 9; ++j) {
                R[j] = lA[9 * t + j];   // R_rel
                A[j] = lB[9 * t + j];   // R_w2c2
                B[j] = lC[9 * t + j];   // R_w2c1
            }
            // M = R_rel^T @ R_w2c2 ; M[i][k] = sum_j R[j][i]*A[j][k]
            float M[9];
            #pragma unroll
            for (int i = 0; i < 3; ++i)
                #pragma unroll
                for (int k = 0; k < 3; ++k)
                    M[3 * i + k] = R[i]     * A[k]
                                 + R[3 + i] * A[3 + k]
                                 + R[6 + i] * A[6 + k];
            // tr = <M, R_w2c1>
            float tr = 0.0f;
            #pragma unroll
            for (int j = 0; j < 9; ++j) tr += M[j] * B[j];

            float cosv  = 0.5f * (tr - 1.0f);
            float cosc  = fminf(fmaxf(cosv, -CLAMP_THR), CLAMP_THR);
            local_loss += acosf(cosc);
            float g = (fabsf(cosv) < CLAMP_THR)
                        ? (-0.5f / sqrtf(1.0f - cosc * cosc))
                        : 0.0f;

            // d_R_w2c1 = g * M  -> lA (own slot, no cross-thread hazard)
            #pragma unroll
            for (int j = 0; j < 9; ++j) lA[9 * t + j] = g * M[j];
            // d_R_w2c2 = g * (R_rel @ R_w2c1) -> lB
            #pragma unroll
            for (int i = 0; i < 3; ++i)
                #pragma unroll
                for (int k = 0; k < 3; ++k)
                    lB[9 * t + 3 * i + k] = g * (R[3 * i]     * B[k]
                                               + R[3 * i + 1] * B[3 + k]
                                               + R[3 * i + 2] * B[6 + k]);
        }
        __syncthreads();

        // ---- LDS -> global stores (coalesced dword; out+1 is unaligned for float4) ----
        for (int i = t; i < vf; i += 256) {
            out1[base + i] = lA[i];
            out2[base + i] = lB[i];
        }
        __syncthreads();  // protect LDS before next chunk's loads
    }

    // ---- loss reduction: wave shuffle -> block -> one atomic per block ----
    #pragma unroll
    for (int off = 32; off > 0; off >>= 1)
        local_loss += __shfl_down(local_loss, off, 64);
    if ((t & 63) == 0) wsum[t >> 6] = local_loss;
    __syncthreads();
    if (t == 0)
        atomicAdd(out, wsum[0] + wsum[1] + wsum[2] + wsum[3]);
}

extern "C" void kernel_launch(void* const* d_in, const int* in_sizes, int n_in,
                              void* d_out, int out_size, void* d_ws, size_t ws_size,
                              hipStream_t stream) {
    const float* Rrel = (const float*)d_in[0];
    const float* Rw1  = (const float*)d_in[1];
    const float* Rw2  = (const float*)d_in[2];
    float* out = (float*)d_out;
    const int n = in_sizes[0] / 9;

    zero_loss_kernel<<<1, 64, 0, stream>>>(out);

    const int nChunks = (n + ELEMS - 1) / ELEMS;
    const int grid = nChunks < 2048 ? nChunks : 2048;
    geodesic_grad_kernel<<<grid, 256, 0, stream>>>(Rrel, Rw1, Rw2, out, n);
}